// Round 2
// baseline (270.604 us; speedup 1.0000x reference)
//
#include <hip/hip_runtime.h>

// FeedForwardQuantum, split into two streaming kernels via q workspace.
// Quantum layer reduced analytically (Clifford circuit):
//   c_i = cos(h_i)
//   q0=c0, q1=c1, q2=c0c2, q3=c1c3, q4=c0c2c4, q5=c1c3c5,
//   q6=c0c2c4c6, q7=c0c1c2c3c4c5c6c7
// i.e. q_f = prefix-product over the parity chain of f, and q7 = pre6*pre7.

constexpr int E       = 1024;
constexpr int R_TOTAL = 8 * 4096;   // 32768 rows
constexpr int ROWS_A  = 32;         // rows per block, kernel A (4 waves x 8)
constexpr int ROWS_B  = 16;         // rows per block, kernel B

// ---------------- Kernel A: x -> q ----------------
__global__ __launch_bounds__(256)
void ffq_qkernel(const float* __restrict__ x,
                 const float* __restrict__ w1,
                 const float* __restrict__ b1,
                 float* __restrict__ q)
{
    // part[row][f*4 + wave]; stride 33 breaks the stride-32 bank pattern
    __shared__ float part[ROWS_A][33];

    const int t    = threadIdx.x;
    const int lane = t & 63;
    const int wid  = t >> 6;
    const int c0   = t * 4;          // this thread's 4 columns of E

    // w1 slice in registers: w1[f][c0..c0+3]
    float4 w1r[8];
#pragma unroll
    for (int f = 0; f < 8; ++f)
        w1r[f] = *(const float4*)(w1 + f * E + c0);

    const int row0 = blockIdx.x * ROWS_A;

    // software-pipelined row loop, single barrier per block
    float4 xv = *(const float4*)(x + (size_t)row0 * E + c0);
    for (int s = 0; s < ROWS_A; ++s) {
        const float4 xc = xv;
        if (s + 1 < ROWS_A)
            xv = *(const float4*)(x + (size_t)(row0 + s + 1) * E + c0);

        float h[8];
#pragma unroll
        for (int f = 0; f < 8; ++f)
            h[f] = xc.x * w1r[f].x + xc.y * w1r[f].y
                 + xc.z * w1r[f].z + xc.w * w1r[f].w;

        // multi-value butterfly: 8 sums across 64 lanes in 6 xor steps.
        // After step 3 lane L holds f = bitrev3(L&7); steps 4-6 all-reduce.
        {   const bool hb = lane & 1;
            float s0 = hb ? h[0] : h[4];
            float s1 = hb ? h[1] : h[5];
            float s2 = hb ? h[2] : h[6];
            float s3 = hb ? h[3] : h[7];
            s0 = __shfl_xor(s0, 1); s1 = __shfl_xor(s1, 1);
            s2 = __shfl_xor(s2, 1); s3 = __shfl_xor(s3, 1);
            h[0] = (hb ? h[4] : h[0]) + s0;
            h[1] = (hb ? h[5] : h[1]) + s1;
            h[2] = (hb ? h[6] : h[2]) + s2;
            h[3] = (hb ? h[7] : h[3]) + s3;
        }
        {   const bool hb = lane & 2;
            float s0 = hb ? h[0] : h[2];
            float s1 = hb ? h[1] : h[3];
            s0 = __shfl_xor(s0, 2); s1 = __shfl_xor(s1, 2);
            h[0] = (hb ? h[2] : h[0]) + s0;
            h[1] = (hb ? h[3] : h[1]) + s1;
        }
        float v;
        {   const bool hb = lane & 4;
            float s0 = hb ? h[0] : h[1];
            s0 = __shfl_xor(s0, 4);
            v = (hb ? h[1] : h[0]) + s0;
        }
        v += __shfl_xor(v, 8);
        v += __shfl_xor(v, 16);
        v += __shfl_xor(v, 32);

        if (lane < 8) {
            const int f = ((lane & 1) << 2) | (lane & 2) | ((lane >> 2) & 1);
            part[s][f * 4 + wid] = v;
        }
    }
    __syncthreads();

    // q-finish, wave-local: wave `wid` handles rows 8*wid .. 8*wid+7.
    // lane = s_local*8 + f
    {
        const int s = wid * 8 + (lane >> 3);
        const int f = lane & 7;
        const float hq = part[s][f * 4 + 0] + part[s][f * 4 + 1]
                       + part[s][f * 4 + 2] + part[s][f * 4 + 3] + b1[f];
        float p = __cosf(hq);
        // parity-chain prefix product within each 8-lane segment
        float u = __shfl_up(p, 2, 8); if (f >= 2) p *= u;
        u = __shfl_up(p, 4, 8);       if (f >= 4) p *= u;
        const float p6 = __shfl(p, 6, 8);   // even-chain full product
        if (f == 7) p *= p6;
        q[(size_t)(row0 + s) * 8 + f] = p;  // 64 contiguous floats per wave
    }
}

// ---------------- Kernel B: q -> out ----------------
__global__ __launch_bounds__(256)
void ffq_okernel(const float* __restrict__ q,
                 const float* __restrict__ w2,
                 const float* __restrict__ b2,
                 float* __restrict__ out)
{
    __shared__ __align__(16) float4 qsh[ROWS_B * 2];  // 16 rows x 8 floats

    const int t  = threadIdx.x;
    const int c0 = t * 4;
    const int row0 = blockIdx.x * ROWS_B;

    if (t < ROWS_B * 2)
        qsh[t] = ((const float4*)(q + (size_t)row0 * 8))[t];

    // w2 slice: w2[c0+j][f] -> w2a[j][f]
    float w2a[4][8];
#pragma unroll
    for (int j = 0; j < 4; ++j) {
        const float4 lo = *(const float4*)(w2 + (size_t)(c0 + j) * 8);
        const float4 hi = *(const float4*)(w2 + (size_t)(c0 + j) * 8 + 4);
        w2a[j][0] = lo.x; w2a[j][1] = lo.y; w2a[j][2] = lo.z; w2a[j][3] = lo.w;
        w2a[j][4] = hi.x; w2a[j][5] = hi.y; w2a[j][6] = hi.z; w2a[j][7] = hi.w;
    }
    const float4 b2v = *(const float4*)(b2 + c0);

    __syncthreads();

#pragma unroll 4
    for (int s = 0; s < ROWS_B; ++s) {
        const float4 qlo = qsh[2 * s];
        const float4 qhi = qsh[2 * s + 1];
        const float qv[8] = {qlo.x, qlo.y, qlo.z, qlo.w,
                             qhi.x, qhi.y, qhi.z, qhi.w};
        float4 o = b2v;
#pragma unroll
        for (int f = 0; f < 8; ++f) {
            o.x += qv[f] * w2a[0][f];
            o.y += qv[f] * w2a[1][f];
            o.z += qv[f] * w2a[2][f];
            o.w += qv[f] * w2a[3][f];
        }
        *(float4*)(out + (size_t)(row0 + s) * E + c0) = o;
    }
}

extern "C" void kernel_launch(void* const* d_in, const int* in_sizes, int n_in,
                              void* d_out, int out_size, void* d_ws, size_t ws_size,
                              hipStream_t stream)
{
    const float* x  = (const float*)d_in[0];
    const float* w1 = (const float*)d_in[1];
    const float* b1 = (const float*)d_in[2];
    const float* w2 = (const float*)d_in[3];
    const float* b2 = (const float*)d_in[4];
    float* out = (float*)d_out;
    float* q   = (float*)d_ws;   // 32768 x 8 floats = 1 MB

    ffq_qkernel<<<dim3(R_TOTAL / ROWS_A), 256, 0, stream>>>(x, w1, b1, q);
    ffq_okernel<<<dim3(R_TOTAL / ROWS_B), 256, 0, stream>>>(q, w2, b2, out);
}

// Round 3
// 263.775 us; speedup vs baseline: 1.0259x; 1.0259x over previous
//
#include <hip/hip_runtime.h>

// FeedForwardQuantum fused: out = q(x@w1^T + b1) @ w2^T + b2
// Quantum layer reduced analytically (Clifford circuit):
//   c_i = cos(h_i)
//   q0=c0, q1=c1, q2=c0c2, q3=c1c3, q4=c0c2c4, q5=c1c3c5,
//   q6=c0c2c4c6, q7=c0c1c2c3c4c5c6c7
// = parity-chain prefix products; q7 = (even chain)*(odd chain).

constexpr int THREADS = 256;
constexpr int TILE    = 32;    // rows per block
constexpr int BATCH   = 8;     // rows per load batch (MLP depth)
constexpr int E       = 1024;
constexpr int R_TOTAL = 8 * 4096;   // 32768 rows

__global__ __launch_bounds__(THREADS, 4)   // cap VGPR<=128 -> 4 waves/SIMD
void ffq_kernel(const float* __restrict__ x,
                const float* __restrict__ w1,
                const float* __restrict__ b1,
                const float* __restrict__ w2,
                const float* __restrict__ b2,
                float* __restrict__ out)
{
    __shared__ float part[TILE][33];            // stride 33: conflict-free
    __shared__ __align__(16) float qsh[TILE][8];
    __shared__ float b1s[8];

    const int t    = threadIdx.x;
    const int lane = t & 63;
    const int wid  = t >> 6;
    const int c0   = t * 4;                     // this thread's 4 columns of E

    if (t < 8) b1s[t] = b1[t];

    // w1 slice in registers: w1[f][c0..c0+3]
    float4 w1r[8];
#pragma unroll
    for (int f = 0; f < 8; ++f)
        w1r[f] = *(const float4*)(w1 + f * E + c0);

    const int row0 = blockIdx.x * TILE;

    // ---------------- phase 1: h partials + in-wave butterfly ----------------
    // 8-row batches, ping-pong buffered: next batch's 8 loads are in flight
    // while the current batch's butterflies run. No barriers in this phase.
    float4 cur[BATCH];
#pragma unroll
    for (int s = 0; s < BATCH; ++s)
        cur[s] = *(const float4*)(x + (size_t)(row0 + s) * E + c0);

#pragma unroll
    for (int b = 0; b < TILE / BATCH; ++b) {
        float4 nxt[BATCH];
        if (b + 1 < TILE / BATCH) {
#pragma unroll
            for (int s = 0; s < BATCH; ++s)
                nxt[s] = *(const float4*)(x + (size_t)(row0 + (b + 1) * BATCH + s) * E + c0);
        }

#pragma unroll
        for (int s = 0; s < BATCH; ++s) {
            const float4 xc = cur[s];
            float h[8];
#pragma unroll
            for (int f = 0; f < 8; ++f)
                h[f] = xc.x * w1r[f].x + xc.y * w1r[f].y
                     + xc.z * w1r[f].z + xc.w * w1r[f].w;

            // multi-value butterfly: 8 sums across 64 lanes, 6 xor steps.
            // After step 3 lane L holds f = bitrev3(L&7); steps 4-6 all-reduce.
            {   const bool hb = lane & 1;
                float s0 = hb ? h[0] : h[4];
                float s1 = hb ? h[1] : h[5];
                float s2 = hb ? h[2] : h[6];
                float s3 = hb ? h[3] : h[7];
                s0 = __shfl_xor(s0, 1); s1 = __shfl_xor(s1, 1);
                s2 = __shfl_xor(s2, 1); s3 = __shfl_xor(s3, 1);
                h[0] = (hb ? h[4] : h[0]) + s0;
                h[1] = (hb ? h[5] : h[1]) + s1;
                h[2] = (hb ? h[6] : h[2]) + s2;
                h[3] = (hb ? h[7] : h[3]) + s3;
            }
            {   const bool hb = lane & 2;
                float s0 = hb ? h[0] : h[2];
                float s1 = hb ? h[1] : h[3];
                s0 = __shfl_xor(s0, 2); s1 = __shfl_xor(s1, 2);
                h[0] = (hb ? h[2] : h[0]) + s0;
                h[1] = (hb ? h[3] : h[1]) + s1;
            }
            float v;
            {   const bool hb = lane & 4;
                float s0 = hb ? h[0] : h[1];
                s0 = __shfl_xor(s0, 4);
                v = (hb ? h[1] : h[0]) + s0;
            }
            v += __shfl_xor(v, 8);
            v += __shfl_xor(v, 16);
            v += __shfl_xor(v, 32);

            if (lane < 8) {
                const int f = ((lane & 1) << 2) | (lane & 2) | ((lane >> 2) & 1);
                part[b * BATCH + s][f * 4 + wid] = v;
            }
        }

#pragma unroll
        for (int s = 0; s < BATCH; ++s) cur[s] = nxt[s];
    }
    __syncthreads();   // barrier 1 of 2

    // ---------------- phase 2: q-finish, all 256 threads ----------------
    // thread t -> row t>>3, feature t&7 (segment-local prefix product)
    {
        const int r = t >> 3;
        const int f = t & 7;
        const float hq = part[r][f * 4 + 0] + part[r][f * 4 + 1]
                       + part[r][f * 4 + 2] + part[r][f * 4 + 3] + b1s[f];
        float p = __cosf(hq);
        float u = __shfl_up(p, 2, 8); if (f >= 2) p *= u;
        u = __shfl_up(p, 4, 8);       if (f >= 4) p *= u;
        const float p6 = __shfl(p, 6, 8);   // even-chain full product
        if (f == 7) p *= p6;
        qsh[r][f] = p;
    }

    // w2/b2 register loads here: latency overlaps q-finish + barrier, and
    // keeps them out of phase-1's register peak.
    float w2a[4][8];
#pragma unroll
    for (int j = 0; j < 4; ++j) {
        const float4 lo = *(const float4*)(w2 + (size_t)(c0 + j) * 8);
        const float4 hi = *(const float4*)(w2 + (size_t)(c0 + j) * 8 + 4);
        w2a[j][0] = lo.x; w2a[j][1] = lo.y; w2a[j][2] = lo.z; w2a[j][3] = lo.w;
        w2a[j][4] = hi.x; w2a[j][5] = hi.y; w2a[j][6] = hi.z; w2a[j][7] = hi.w;
    }
    const float4 b2v = *(const float4*)(b2 + c0);

    __syncthreads();   // barrier 2 of 2

    // ---------------- phase 3: out = q @ w2^T + b2 ----------------
#pragma unroll 8
    for (int s = 0; s < TILE; ++s) {
        const float4 qlo = *(const float4*)(&qsh[s][0]);   // broadcast reads
        const float4 qhi = *(const float4*)(&qsh[s][4]);
        const float qv[8] = {qlo.x, qlo.y, qlo.z, qlo.w,
                             qhi.x, qhi.y, qhi.z, qhi.w};
        float4 o = b2v;
#pragma unroll
        for (int f = 0; f < 8; ++f) {
            o.x += qv[f] * w2a[0][f];
            o.y += qv[f] * w2a[1][f];
            o.z += qv[f] * w2a[2][f];
            o.w += qv[f] * w2a[3][f];
        }
        *(float4*)(out + (size_t)(row0 + s) * E + c0) = o;
    }
}

extern "C" void kernel_launch(void* const* d_in, const int* in_sizes, int n_in,
                              void* d_out, int out_size, void* d_ws, size_t ws_size,
                              hipStream_t stream)
{
    const float* x  = (const float*)d_in[0];
    const float* w1 = (const float*)d_in[1];
    const float* b1 = (const float*)d_in[2];
    const float* w2 = (const float*)d_in[3];
    const float* b2 = (const float*)d_in[4];
    float* out = (float*)d_out;

    ffq_kernel<<<dim3(R_TOTAL / TILE), THREADS, 0, stream>>>(x, w1, b1, w2, b2, out);
}

// Round 4
// 244.376 us; speedup vs baseline: 1.1073x; 1.0794x over previous
//
#include <hip/hip_runtime.h>

// FeedForwardQuantum fused: out = q(x@w1^T + b1) @ w2^T + b2
// Quantum layer reduced analytically (Clifford circuit):
//   c_i = cos(h_i)
//   q0=c0, q1=c1, q2=c0c2, q3=c1c3, q4=c0c2c4, q5=c1c3c5,
//   q6=c0c2c4c6, q7=c0c1c2c3c4c5c6c7
// = parity-chain prefix products; q7 = (even chain)*(odd chain).

constexpr int THREADS = 256;
constexpr int TILE    = 16;         // rows per block
constexpr int E       = 1024;
constexpr int R_TOTAL = 8 * 4096;   // 32768 rows -> 2048 blocks -> 8 blocks/CU

__global__ __launch_bounds__(THREADS, 8)   // pin VGPR<=64 -> 8 waves/SIMD
void ffq_kernel(const float* __restrict__ x,
                const float* __restrict__ w1,
                const float* __restrict__ b1,
                const float* __restrict__ w2,
                const float* __restrict__ b2,
                float* __restrict__ out)
{
    __shared__ float part[TILE][33];            // stride 33: conflict-free
    __shared__ __align__(16) float qsh[TILE][8];
    __shared__ float b1s[8];

    const int t    = threadIdx.x;
    const int lane = t & 63;
    const int wid  = t >> 6;
    const int c0   = t * 4;                     // this thread's 4 columns of E

    if (t < 8) b1s[t] = b1[t];

    // w1 slice in registers: w1[f][c0..c0+3]  (dead after phase 1; compiler
    // reuses these regs for w2a, keeping peak ~60 VGPRs)
    float4 w1r[8];
#pragma unroll
    for (int f = 0; f < 8; ++f)
        w1r[f] = *(const float4*)(w1 + f * E + c0);

    const int row0 = blockIdx.x * TILE;

    // ---------------- phase 1: h partials + in-wave butterfly ----------------
    // depth-2 software pipeline (cur/nxt stays register-resident), no barriers.
    float4 cur = *(const float4*)(x + (size_t)row0 * E + c0);
#pragma unroll
    for (int s = 0; s < TILE; ++s) {
        const float4 xc = cur;
        if (s + 1 < TILE)
            cur = *(const float4*)(x + (size_t)(row0 + s + 1) * E + c0);

        float h[8];
#pragma unroll
        for (int f = 0; f < 8; ++f)
            h[f] = xc.x * w1r[f].x + xc.y * w1r[f].y
                 + xc.z * w1r[f].z + xc.w * w1r[f].w;

        // multi-value butterfly: 8 sums across 64 lanes, 6 xor steps.
        // After step 3 lane L holds f = bitrev3(L&7); steps 4-6 all-reduce.
        {   const bool hb = lane & 1;
            float s0 = hb ? h[0] : h[4];
            float s1 = hb ? h[1] : h[5];
            float s2 = hb ? h[2] : h[6];
            float s3 = hb ? h[3] : h[7];
            s0 = __shfl_xor(s0, 1); s1 = __shfl_xor(s1, 1);
            s2 = __shfl_xor(s2, 1); s3 = __shfl_xor(s3, 1);
            h[0] = (hb ? h[4] : h[0]) + s0;
            h[1] = (hb ? h[5] : h[1]) + s1;
            h[2] = (hb ? h[6] : h[2]) + s2;
            h[3] = (hb ? h[7] : h[3]) + s3;
        }
        {   const bool hb = lane & 2;
            float s0 = hb ? h[0] : h[2];
            float s1 = hb ? h[1] : h[3];
            s0 = __shfl_xor(s0, 2); s1 = __shfl_xor(s1, 2);
            h[0] = (hb ? h[2] : h[0]) + s0;
            h[1] = (hb ? h[3] : h[1]) + s1;
        }
        float v;
        {   const bool hb = lane & 4;
            float s0 = hb ? h[0] : h[1];
            s0 = __shfl_xor(s0, 4);
            v = (hb ? h[1] : h[0]) + s0;
        }
        v += __shfl_xor(v, 8);
        v += __shfl_xor(v, 16);
        v += __shfl_xor(v, 32);

        if (lane < 8) {
            const int f = ((lane & 1) << 2) | (lane & 2) | ((lane >> 2) & 1);
            part[s][f * 4 + wid] = v;
        }
    }
    __syncthreads();   // barrier 1 of 2

    // ---------------- phase 2: q-finish (threads 0..127) ----------------
    // thread t -> row t>>3, feature t&7 (segment-local prefix product)
    if (t < TILE * 8) {
        const int r = t >> 3;
        const int f = t & 7;
        const float hq = part[r][f * 4 + 0] + part[r][f * 4 + 1]
                       + part[r][f * 4 + 2] + part[r][f * 4 + 3] + b1s[f];
        float p = __cosf(hq);
        float u = __shfl_up(p, 2, 8); if (f >= 2) p *= u;
        u = __shfl_up(p, 4, 8);       if (f >= 4) p *= u;
        const float p6 = __shfl(p, 6, 8);   // even-chain full product
        if (f == 7) p *= p6;
        qsh[r][f] = p;
    }

    // w2/b2 register loads here: latency overlaps q-finish + barrier, and
    // keeps them out of phase-1's register peak (w1r regs now dead).
    float w2a[4][8];
#pragma unroll
    for (int j = 0; j < 4; ++j) {
        const float4 lo = *(const float4*)(w2 + (size_t)(c0 + j) * 8);
        const float4 hi = *(const float4*)(w2 + (size_t)(c0 + j) * 8 + 4);
        w2a[j][0] = lo.x; w2a[j][1] = lo.y; w2a[j][2] = lo.z; w2a[j][3] = lo.w;
        w2a[j][4] = hi.x; w2a[j][5] = hi.y; w2a[j][6] = hi.z; w2a[j][7] = hi.w;
    }
    const float4 b2v = *(const float4*)(b2 + c0);

    __syncthreads();   // barrier 2 of 2

    // ---------------- phase 3: out = q @ w2^T + b2 ----------------
#pragma unroll
    for (int s = 0; s < TILE; ++s) {
        const float4 qlo = *(const float4*)(&qsh[s][0]);   // broadcast reads
        const float4 qhi = *(const float4*)(&qsh[s][4]);
        const float qv[8] = {qlo.x, qlo.y, qlo.z, qlo.w,
                             qhi.x, qhi.y, qhi.z, qhi.w};
        float4 o = b2v;
#pragma unroll
        for (int f = 0; f < 8; ++f) {
            o.x += qv[f] * w2a[0][f];
            o.y += qv[f] * w2a[1][f];
            o.z += qv[f] * w2a[2][f];
            o.w += qv[f] * w2a[3][f];
        }
        *(float4*)(out + (size_t)(row0 + s) * E + c0) = o;
    }
}

extern "C" void kernel_launch(void* const* d_in, const int* in_sizes, int n_in,
                              void* d_out, int out_size, void* d_ws, size_t ws_size,
                              hipStream_t stream)
{
    const float* x  = (const float*)d_in[0];
    const float* w1 = (const float*)d_in[1];
    const float* b1 = (const float*)d_in[2];
    const float* w2 = (const float*)d_in[3];
    const float* b2 = (const float*)d_in[4];
    float* out = (float*)d_out;

    ffq_kernel<<<dim3(R_TOTAL / TILE), THREADS, 0, stream>>>(x, w1, b1, w2, b2, out);
}